// Round 3
// baseline (617.423 us; speedup 1.0000x reference)
//
#include <hip/hip_runtime.h>

// LSTM B=32768, T=512, I=2, H=16 — MFMA recurrence v4:
// v3 structure (unit-major tiles, x/bias folded into MFMA, ping-pong B frags)
// + TRANSCENDENTAL-FREE activations via the exact tanh continued fraction
//   [5/6] Pade: tanh(y) = y*(10395 + 1260u + 21u^2)/(10395 + 4725u + 210u^2 + u^3),
//   u = y^2  (error <= 1e-4 for |y|<=3.5, <= 3e-3 at |y|=6).
// sigma(x) = 0.5 + 0.5*tanh(x/2): the /2 is folded into the gate weights.
// Per unit-step: 7 trans (5 exp2 + 2 rcp) -> 1.5 rcp:
//   * the 4 gate denominators share ONE rcp via batch-inversion
//   * tanh(c) denominators share one rcp per tile PAIR
// State is s = 2c; h is packed as h2 = 2h = fma(To,Tc,Tc) with W_hh
// pre-scaled by an extra 0.5. All 0.5's folded into CF constants / scales:
//   tanh(s/2) = s*(5197.5 + 157.5w + 0.65625w^2) /
//               (10395 + 1181.25w + 13.125w^2 + 0.015625w^3),  w = s^2
//   s' = fma(0.5, fma(Tf,s,s), fma(Ti,Tg,Tg));  h2 = fma(To,Tc,Tc)
// Gate math runs pairwise in f32x2 -> v_pk_* on gfx950.

#define T_STEPS 512
#define LOG2E 1.44269504088896340736f

typedef __bf16 bf16x8 __attribute__((ext_vector_type(8)));
typedef float  f32x4  __attribute__((ext_vector_type(4)));
typedef float  f32x2  __attribute__((ext_vector_type(2)));
typedef unsigned int u32x4 __attribute__((ext_vector_type(4)));

union frag_u { u32x4 u; bf16x8 v; };

#if __has_builtin(__builtin_amdgcn_exp2f)
__device__ __forceinline__ float fexp2(float x) { return __builtin_amdgcn_exp2f(x); }
#else
__device__ __forceinline__ float fexp2(float x) { return exp2f(x); }
#endif
#if __has_builtin(__builtin_amdgcn_rcpf)
__device__ __forceinline__ float frcp(float x) { return __builtin_amdgcn_rcpf(x); }
#else
__device__ __forceinline__ float frcp(float x) { return 1.0f / x; }
#endif

// (hi,hi) duplicate of the bf16-truncated value: one v_perm.
__device__ __forceinline__ unsigned dup_hi(float h) {
    unsigned hb = __float_as_uint(h);
#if __has_builtin(__builtin_amdgcn_perm)
    return __builtin_amdgcn_perm(hb, hb, 0x03020302u);
#else
    return (hb >> 16) | (hb & 0xFFFF0000u);
#endif
}
// low16 = bf16(res) of h, high16 = high16 of xq (x part, bf16-in-high16).
__device__ __forceinline__ unsigned lo_with_x(float res, unsigned xq) {
#if __has_builtin(__builtin_amdgcn_perm)
    return __builtin_amdgcn_perm(xq, __float_as_uint(res), 0x07060302u);
#else
    return (__float_as_uint(res) >> 16) | (xq & 0xFFFF0000u);
#endif
}
// setup-only: (hi,lo) k-interleaved pack for the A fragment
__device__ __forceinline__ unsigned pack_hilo(float h) {
    unsigned hb = __float_as_uint(h);
    float    res = h - __uint_as_float(hb & 0xFFFF0000u);
#if __has_builtin(__builtin_amdgcn_perm)
    return __builtin_amdgcn_perm(__float_as_uint(res), hb, 0x07060302u);
#else
    return (hb >> 16) | (__float_as_uint(res) & 0xFFFF0000u);
#endif
}
// bf16 (truncated) of v, placed in HIGH 16 bits, low16 zero.
__device__ __forceinline__ unsigned bfhi(float v) {
    return __float_as_uint(v) & 0xFFFF0000u;
}
// x part for this lane's q: col = q>=2, part (hi/lo) = q&1; bf16 in high16.
__device__ __forceinline__ unsigned make_xq(float nx0, float nx1, int q) {
    const float xs = (q & 2) ? nx1 : nx0;
    const unsigned h16 = bfhi(xs);
    const unsigned l16 = bfhi(xs - __uint_as_float(h16));
    return (q & 1) ? l16 : h16;
}

// One LSTM step: reads (BhI, BlI), writes (BhO, BlO). Ping-pong caller-side.
// cst[t] = 2*c of unit 4t+q. CF-rational activations, 1.5 rcp per tile.
__device__ __forceinline__ void lstm_step(
    const frag_u& BhI, const frag_u& BlI,
    frag_u& BhO, frag_u& BlO,
    float cst[4],
    const frag_u A1[4], const frag_u A2[4], const f32x4 biasf[4],
    unsigned xqn)
{
    f32x4 acc[4];
    #pragma unroll
    for (int t = 0; t < 4; ++t)
        acc[t] = __builtin_amdgcn_mfma_f32_16x16x32_bf16(A1[t].v, BhI.v, biasf[t], 0, 0, 0);

    #pragma unroll
    for (int pp = 0; pp < 2; ++pp) {
        float numc2[2], dc2[2], To2[2];
        #pragma unroll
        for (int tt = 0; tt < 2; ++tt) {
            const int t = 2 * pp + tt;
            acc[t] = __builtin_amdgcn_mfma_f32_16x16x32_bf16(A2[t].v, BlI.v, acc[t], 0, 0, 0);

            f32x2 a, b;                      // a = (yi, yf), b = (yg, yo)
            a.x = acc[t][0]; a.y = acc[t][1];
            b.x = acc[t][2]; b.y = acc[t][3];

            const f32x2 ua = a * a, ub = b * b;
            f32x2 na = ua * 21.0f + 1260.0f;  na = ua * na + 10395.0f;
            f32x2 nb = ub * 21.0f + 1260.0f;  nb = ub * nb + 10395.0f;
            const f32x2 numa = a * na;
            const f32x2 numb = b * nb;
            f32x2 da = ua + 210.0f; da = ua * da + 4725.0f; da = ua * da + 10395.0f;
            f32x2 db = ub + 210.0f; db = ub * db + 4725.0f; db = ub * db + 10395.0f;

            const float p1 = da.x * da.y, p2 = db.x * db.y;
            const float r  = frcp(p1 * p2);              // ONE rcp for 4 gates
            const float Ti = numa.x * ((da.y * p2) * r); // tanh(pre_i/2)
            const float Tf = numa.y * ((da.x * p2) * r);
            const float Tg = numb.x * ((db.y * p1) * r); // tanh(pre_g)
            const float To = numb.y * ((db.x * p1) * r);

            const float mf = fmaf(Tf, cst[t], cst[t]);   // (1+Tf)*s
            const float mg = fmaf(Ti, Tg, Tg);           // (1+Ti)*Tg
            const float sn = fmaf(0.5f, mf, mg);         // s' = 2c'
            cst[t] = sn;

            const float yc = fminf(fmaxf(sn, -12.0f), 12.0f);  // clamp c to +-6
            const float w  = yc * yc;
            float nc = fmaf(w, 0.65625f, 157.5f);  nc = fmaf(w, nc, 5197.5f);
            numc2[tt] = yc * nc;
            float dc = fmaf(w, 0.015625f, 13.125f); dc = fmaf(w, dc, 1181.25f);
            dc2[tt] = fmaf(w, dc, 10395.0f);
            To2[tt] = To;
        }
        const float rq = frcp(dc2[0] * dc2[1]);          // one rcp per tile pair
        #pragma unroll
        for (int tt = 0; tt < 2; ++tt) {
            const int t = 2 * pp + tt;
            const float Tc = numc2[tt] * (rq * dc2[1 - tt]);   // tanh(c')
            const float h2 = fmaf(To2[tt], Tc, Tc);            // 2h = (1+To)Tc

            const unsigned hb = __float_as_uint(h2);
            BhO.u[t] = dup_hi(h2);
            const float resf = h2 - __uint_as_float(hb & 0xFFFF0000u);
            BlO.u[t] = lo_with_x(resf, xqn);
        }
    }
}

__global__ __launch_bounds__(256, 2)
void lstm_mfma_kernel(const float* __restrict__ x,
                      const float* __restrict__ W_ih,
                      const float* __restrict__ W_hh,
                      const float* __restrict__ b_ih,
                      const float* __restrict__ b_hh,
                      const float* __restrict__ W1,
                      const float* __restrict__ b1,
                      const float* __restrict__ W2,
                      const float* __restrict__ b2,
                      float* __restrict__ out)
{
    __shared__ float hsm[4][16][16];   // head only; per-wave private, no barriers

    const int tid  = threadIdx.x;
    const int wv   = tid >> 6;
    const int lane = tid & 63;
    const int e    = lane & 15;        // elem within wave (C/D col, B col)
    const int q    = lane >> 4;        // quad (C/D row block, A/B k block)
    const int m    = lane & 15;        // A row within tile

    // pre-act -> CF-argument scales (gate order i,f,g,o along m&3):
    //   i,f,o: y = pre/2 ; g: y = pre.  W_hh gets an extra 0.5 (B carries 2h).
    const float gsc[4]  = { 0.5f, 0.5f, 1.0f, 0.5f };    // W_ih, bias
    const float gscW[4] = { 0.25f, 0.25f, 0.5f, 0.25f }; // W_hh

    // ---- static fragments ---------------------------------------------------
    frag_u A1[4], A2[4];
    f32x4  biasf[4];
    #pragma unroll
    for (int t = 0; t < 4; ++t) {
        const int   g  = m & 3;
        const int   Rr = g * 16 + 4 * t + (m >> 2);
        const float sc  = gsc[g];
        const float scW = gscW[g];

        const float xw0 = W_ih[Rr * 2 + 0] * sc;
        const float xw1 = W_ih[Rr * 2 + 1] * sc;
        const unsigned x0h = bfhi(xw0);
        const unsigned x0l = bfhi(xw0 - __uint_as_float(x0h));
        const unsigned x1h = bfhi(xw1);
        const unsigned x1l = bfhi(xw1 - __uint_as_float(x1h));
        const unsigned cw0 = (q < 2) ? x0h : x1h;   // w=0: hi coefficient
        const unsigned cw1 = (q < 2) ? x0l : x1l;   // w=1: lo coefficient

        #pragma unroll
        for (int w = 0; w < 4; ++w) {
            const float whh = W_hh[Rr * 16 + 4 * w + q] * scW;
            A1[t].u[w] = pack_hilo(whh);
            A2[t].u[w] = __float_as_uint(whh) >> 16;   // even k: W_hi, odd k: 0
        }
        A2[t].u[0] |= cw0;
        A2[t].u[1] |= cw1;

        #pragma unroll
        for (int j = 0; j < 4; ++j) {
            const int Rb = j * 16 + 4 * t + q;
            biasf[t][j] = (b_ih[Rb] + b_hh[Rb]) * gsc[j];
        }
    }

    const int gelem = blockIdx.x * 64 + wv * 16 + e;
    const float4* xp = (const float4*)(x + (size_t)gelem * (T_STEPS * 2));

    frag_u BhA, BlA, BhB, BlB;                 // ping-pong h fragments (2h packs)
    float  cst[4] = {0.f, 0.f, 0.f, 0.f};      // s = 2c, unit 4t+q

    float4 xv = xp[0];

    // prologue: BhA = 0 (h_-1 = 0); BlA odd slots = x for step 0, low16 = 0.
    {
        const unsigned xq0 = make_xq(xv.x, xv.y, q);
        #pragma unroll
        for (int w = 0; w < 4; ++w) { BhA.u[w] = 0u; BlA.u[w] = xq0; }
    }

    for (int t2 = 0; t2 < T_STEPS / 2; ++t2) {
        const float4 xnext = xp[(t2 + 1) & (T_STEPS / 2 - 1)];

        // x parts for steps s0+1 and s0+2 (independent: fill MFMA shadow)
        const unsigned xq1 = make_xq(xv.z, xv.w, q);
        const unsigned xq2 = make_xq(xnext.x, xnext.y, q);

        lstm_step(BhA, BlA, BhB, BlB, cst, A1, A2, biasf, xq1);  // step s0
        lstm_step(BhB, BlB, BhA, BlA, cst, A1, A2, biasf, xq2);  // step s0+1

        xv = xnext;
    }

    // ---- MLP head: z = tanh(W1 h + b1); y = W2 z + b2. Intra-wave, no barrier.
    #pragma unroll
    for (int r = 0; r < 4; ++r) {
        const float hval = 0.5f * (__uint_as_float(BhA.u[r] << 16) +   // hi of 2h
                                   __uint_as_float(BlA.u[r] << 16));   // lo of 2h
        hsm[wv][e][4 * r + q] = hval;                                  // unit 4r+q
    }

    float hv[16];
    #pragma unroll
    for (int j = 0; j < 4; ++j) {
        const float4 t4 = *(const float4*)&hsm[wv][e][4 * j];
        hv[4 * j + 0] = t4.x; hv[4 * j + 1] = t4.y;
        hv[4 * j + 2] = t4.z; hv[4 * j + 3] = t4.w;
    }

    float z[4];
    #pragma unroll
    for (int r = 0; r < 4; ++r) {
        const int mm = 4 * q + r;
        float a = b1[mm];
        #pragma unroll
        for (int j = 0; j < 16; ++j) a = fmaf(W1[mm * 16 + j], hv[j], a);
        const float E = fexp2(a * (2.0f * LOG2E));
        z[r] = fmaf(-2.0f, frcp(1.0f + E), 1.0f);   // safe at +-inf
    }
    #pragma unroll
    for (int r = 0; r < 4; ++r) hsm[wv][e][4 * q + r] = z[r];

    if (q < 2) {
        float a = b2[q];
        #pragma unroll
        for (int j = 0; j < 16; ++j) a = fmaf(W2[q * 16 + j], hsm[wv][e][j], a);
        out[(size_t)gelem * 2 + q] = a;
    }
}

extern "C" void kernel_launch(void* const* d_in, const int* in_sizes, int n_in,
                              void* d_out, int out_size, void* d_ws, size_t ws_size,
                              hipStream_t stream) {
    const float* x    = (const float*)d_in[0];
    const float* W_ih = (const float*)d_in[1];
    const float* W_hh = (const float*)d_in[2];
    const float* b_ih = (const float*)d_in[3];
    const float* b_hh = (const float*)d_in[4];
    const float* W1   = (const float*)d_in[5];
    const float* b1   = (const float*)d_in[6];
    const float* W2   = (const float*)d_in[7];
    const float* b2   = (const float*)d_in[8];
    float* out = (float*)d_out;

    // 32768 elems / 64 per block (4 waves x 16) = 512 blocks
    lstm_mfma_kernel<<<dim3(512), dim3(256), 0, stream>>>(
        x, W_ih, W_hh, b_ih, b_hh, W1, b1, W2, b2, out);
}

// Round 4
// 498.084 us; speedup vs baseline: 1.2396x; 1.2396x over previous
//
#include <hip/hip_runtime.h>

// LSTM B=32768, T=512, I=2, H=16 — MFMA recurrence v5:
// v3 math EXACTLY (exp2-domain gates, single-rcp gate fusion, x/bias in MFMA,
// ping-pong frags) + DUAL SEQUENCE GROUPS per wave + stage-vectorized
// activation across 8 independent chains (2 groups x 4 tiles).
//
// Rationale (r3 post-mortem): 2048 waves = 2/SIMD is fixed by B/16 with one
// group per wave; the per-step serial chain (MFMA1->MFMA2->activation->pack)
// was latency-exposed (VALUBusy ~70% incl. operand stalls, wall ~886cy/step
// vs ~212cy issue census). Two groups/wave doubles independent work per
// SIMD; stage-major activation code guarantees >=8 independent instrs
// between dependent hops regardless of scheduler. Waves: 1024 (1/SIMD),
// grid 256 blocks x 256 thr, launch_bounds(256,1) -> VGPR cap 512.
//
// Per group, per step (identical to v3):
//   MFMA1: A1=(W_hi,W_lo) x Bh=(h_hi,h_hi), C = bias
//   MFMA2: A2=(W_hi | xW)  x Bl=(h_lo, x)
//   I,F,G,O = exp2(gate'); P1=(1+I)(1+G); P2=(1+F)(1+O); R=rcp(P1*P2)
//   cs' = R * fma(P1*Op, cs, 2L(G-1)*P2)   [cs = 2*log2e*c domain]
//   tanh(c)=1-2*rcp(1+exp2(cs'));  h = (P1*Fp)*R * tanh(c)

#define T_STEPS 512
#define LOG2E 1.44269504088896340736f

typedef __bf16 bf16x8 __attribute__((ext_vector_type(8)));
typedef float  f32x4  __attribute__((ext_vector_type(4)));
typedef float  f32x2  __attribute__((ext_vector_type(2)));
typedef unsigned int u32x4 __attribute__((ext_vector_type(4)));

union frag_u { u32x4 u; bf16x8 v; };

#if __has_builtin(__builtin_amdgcn_exp2f)
__device__ __forceinline__ float fexp2(float x) { return __builtin_amdgcn_exp2f(x); }
#else
__device__ __forceinline__ float fexp2(float x) { return exp2f(x); }
#endif
#if __has_builtin(__builtin_amdgcn_rcpf)
__device__ __forceinline__ float frcp(float x) { return __builtin_amdgcn_rcpf(x); }
#else
__device__ __forceinline__ float frcp(float x) { return 1.0f / x; }
#endif

// (hi,hi) duplicate of the bf16-truncated value: one v_perm.
__device__ __forceinline__ unsigned dup_hi(float h) {
    unsigned hb = __float_as_uint(h);
#if __has_builtin(__builtin_amdgcn_perm)
    return __builtin_amdgcn_perm(hb, hb, 0x03020302u);
#else
    return (hb >> 16) | (hb & 0xFFFF0000u);
#endif
}
// low16 = bf16(res) of h, high16 = high16 of xq (x part, bf16-in-high16).
__device__ __forceinline__ unsigned lo_with_x(float res, unsigned xq) {
#if __has_builtin(__builtin_amdgcn_perm)
    return __builtin_amdgcn_perm(xq, __float_as_uint(res), 0x07060302u);
#else
    return (__float_as_uint(res) >> 16) | (xq & 0xFFFF0000u);
#endif
}
// setup-only: (hi,lo) k-interleaved pack for the A fragment
__device__ __forceinline__ unsigned pack_hilo(float h) {
    unsigned hb = __float_as_uint(h);
    float    res = h - __uint_as_float(hb & 0xFFFF0000u);
#if __has_builtin(__builtin_amdgcn_perm)
    return __builtin_amdgcn_perm(__float_as_uint(res), hb, 0x07060302u);
#else
    return (hb >> 16) | (__float_as_uint(res) & 0xFFFF0000u);
#endif
}
// bf16 (truncated) of v, placed in HIGH 16 bits, low16 zero.
__device__ __forceinline__ unsigned bfhi(float v) {
    return __float_as_uint(v) & 0xFFFF0000u;
}
// x part for this lane's q: col = q>=2, part (hi/lo) = q&1; bf16 in high16.
__device__ __forceinline__ unsigned make_xq(float nx0, float nx1, int q) {
    const float xs = (q & 2) ? nx1 : nx0;
    const unsigned h16 = bfhi(xs);
    const unsigned l16 = bfhi(xs - __uint_as_float(h16));
    return (q & 1) ? l16 : h16;
}

// One LSTM step for BOTH groups. Reads BhI[g]/BlI[g], writes BhO[g]/BlO[g].
// Activation is stage-major over the 8 chains (g,t): every dependent hop is
// separated by >=8 independent instructions.
__device__ __forceinline__ void lstm_step_dual(
    const frag_u BhI[2], const frag_u BlI[2],
    frag_u BhO[2], frag_u BlO[2],
    float cst[2][4],
    const frag_u A1[4], const frag_u A2[4], const f32x4 biasf[4],
    unsigned xqA, unsigned xqB)
{
    f32x4 acc[2][4];
    #pragma unroll
    for (int g = 0; g < 2; ++g)
        #pragma unroll
        for (int t = 0; t < 4; ++t)
            acc[g][t] = __builtin_amdgcn_mfma_f32_16x16x32_bf16(A1[t].v, BhI[g].v, biasf[t], 0, 0, 0);
    #pragma unroll
    for (int g = 0; g < 2; ++g)
        #pragma unroll
        for (int t = 0; t < 4; ++t)
            acc[g][t] = __builtin_amdgcn_mfma_f32_16x16x32_bf16(A2[t].v, BlI[g].v, acc[g][t], 0, 0, 0);

    // ---- stage-vectorized activation over 8 chains ----
    f32x2 eIF[2][4], eGO[2][4];
    #pragma unroll
    for (int g = 0; g < 2; ++g)
        #pragma unroll
        for (int t = 0; t < 4; ++t) {
            eIF[g][t].x = fexp2(acc[g][t][0]);   // I
            eIF[g][t].y = fexp2(acc[g][t][1]);   // F
            eGO[g][t].x = fexp2(acc[g][t][2]);   // G
            eGO[g][t].y = fexp2(acc[g][t][3]);   // O
        }

    float Gm[2][4];
    #pragma unroll
    for (int g = 0; g < 2; ++g)
        #pragma unroll
        for (int t = 0; t < 4; ++t)
            Gm[g][t] = fmaf(2.0f * LOG2E, eGO[g][t].x, -2.0f * LOG2E); // 2L(G-1)

    f32x2 pA[2][4], pB[2][4];
    #pragma unroll
    for (int g = 0; g < 2; ++g)
        #pragma unroll
        for (int t = 0; t < 4; ++t) {
            pA[g][t] = eIF[g][t] + 1.0f;         // (Ip, Fp)
            pB[g][t] = eGO[g][t] + 1.0f;         // (Gp, Op)
        }

    f32x2 PP[2][4];
    #pragma unroll
    for (int g = 0; g < 2; ++g)
        #pragma unroll
        for (int t = 0; t < 4; ++t)
            PP[g][t] = pA[g][t] * pB[g][t];      // (P1, P2)

    float d[2][4], tso[2][4], tsf[2][4], gmp[2][4];
    #pragma unroll
    for (int g = 0; g < 2; ++g)
        #pragma unroll
        for (int t = 0; t < 4; ++t) {
            d[g][t]   = PP[g][t].x * PP[g][t].y;
            tso[g][t] = PP[g][t].x * pA[g][t].y;     // so * (P1*P2)
            tsf[g][t] = PP[g][t].x * pB[g][t].y;     // sf * (P1*P2)
            gmp[g][t] = Gm[g][t]   * PP[g][t].y;     // 2L*si*tg * (P1*P2)
        }

    float R[2][4];
    #pragma unroll
    for (int g = 0; g < 2; ++g)
        #pragma unroll
        for (int t = 0; t < 4; ++t)
            R[g][t] = frcp(d[g][t]);                 // one rcp per chain

    float csn[2][4];
    #pragma unroll
    for (int g = 0; g < 2; ++g)
        #pragma unroll
        for (int t = 0; t < 4; ++t) {
            csn[g][t] = fmaf(tsf[g][t], cst[g][t], gmp[g][t]) * R[g][t];
            cst[g][t] = csn[g][t];
        }

    float C2[2][4];
    #pragma unroll
    for (int g = 0; g < 2; ++g)
        #pragma unroll
        for (int t = 0; t < 4; ++t)
            C2[g][t] = fexp2(csn[g][t]);

    float Rd[2][4];
    #pragma unroll
    for (int g = 0; g < 2; ++g)
        #pragma unroll
        for (int t = 0; t < 4; ++t)
            Rd[g][t] = frcp(C2[g][t] + 1.0f);

    #pragma unroll
    for (int g = 0; g < 2; ++g)
        #pragma unroll
        for (int t = 0; t < 4; ++t) {
            const float tc = fmaf(-2.0f, Rd[g][t], 1.0f);      // tanh(c)
            const float hn = (tso[g][t] * R[g][t]) * tc;       // so*tanh(c)
            const unsigned hb = __float_as_uint(hn);
            BhO[g].u[t] = dup_hi(hn);
            const float resf = hn - __uint_as_float(hb & 0xFFFF0000u);
            BlO[g].u[t] = lo_with_x(resf, g ? xqB : xqA);
        }
}

__global__ __launch_bounds__(256, 1)
void lstm_mfma_kernel(const float* __restrict__ x,
                      const float* __restrict__ W_ih,
                      const float* __restrict__ W_hh,
                      const float* __restrict__ b_ih,
                      const float* __restrict__ b_hh,
                      const float* __restrict__ W1,
                      const float* __restrict__ b1,
                      const float* __restrict__ W2,
                      const float* __restrict__ b2,
                      float* __restrict__ out)
{
    __shared__ float hsm[2][4][16][16];   // [group][wave][e][unit] head scratch

    const int tid  = threadIdx.x;
    const int wv   = tid >> 6;
    const int lane = tid & 63;
    const int e    = lane & 15;        // elem within group (C/D col, B col)
    const int q    = lane >> 4;        // quad (C/D row block, A/B k block)
    const int m    = lane & 15;        // A row within tile

    // per-gate exp2-argument scales (gate order i,f,g,o along m&3)
    const float gsc[4] = { -LOG2E, -LOG2E, 2.0f * LOG2E, -LOG2E };

    // ---- static fragments (shared by both groups) ---------------------------
    frag_u A1[4], A2[4];
    f32x4  biasf[4];
    #pragma unroll
    for (int t = 0; t < 4; ++t) {
        const int   g  = m & 3;
        const int   Rr = g * 16 + 4 * t + (m >> 2);
        const float sc = gsc[g];

        const float xw0 = W_ih[Rr * 2 + 0] * sc;
        const float xw1 = W_ih[Rr * 2 + 1] * sc;
        const unsigned x0h = bfhi(xw0);
        const unsigned x0l = bfhi(xw0 - __uint_as_float(x0h));
        const unsigned x1h = bfhi(xw1);
        const unsigned x1l = bfhi(xw1 - __uint_as_float(x1h));
        const unsigned cw0 = (q < 2) ? x0h : x1h;   // w=0: hi coefficient
        const unsigned cw1 = (q < 2) ? x0l : x1l;   // w=1: lo coefficient

        #pragma unroll
        for (int w = 0; w < 4; ++w) {
            const float whh = W_hh[Rr * 16 + 4 * w + q] * sc;
            A1[t].u[w] = pack_hilo(whh);
            A2[t].u[w] = __float_as_uint(whh) >> 16;   // even k: W_hi, odd k: 0
        }
        A2[t].u[0] |= cw0;
        A2[t].u[1] |= cw1;

        #pragma unroll
        for (int j = 0; j < 4; ++j) {
            const int Rb = j * 16 + 4 * t + q;
            biasf[t][j] = (b_ih[Rb] + b_hh[Rb]) * gsc[j];
        }
    }

    // two independent sequence groups per wave: 32 batch elems
    const int gelemA = blockIdx.x * 128 + wv * 32 + e;
    const int gelemB = gelemA + 16;
    const float4* xpA = (const float4*)(x + (size_t)gelemA * (T_STEPS * 2));
    const float4* xpB = (const float4*)(x + (size_t)gelemB * (T_STEPS * 2));

    frag_u BhP[2], BlP[2], BhQ[2], BlQ[2];     // ping-pong frags per group
    float  cst[2][4];                          // cs = 2log2e*c, [group][tile]
    #pragma unroll
    for (int g = 0; g < 2; ++g)
        #pragma unroll
        for (int t = 0; t < 4; ++t) cst[g][t] = 0.0f;

    float4 xvA = xpA[0];
    float4 xvB = xpB[0];

    // prologue: Bh = 0 (h_-1 = 0); Bl odd slots = x for step 0, low16 = 0.
    {
        const unsigned xA0 = make_xq(xvA.x, xvA.y, q);
        const unsigned xB0 = make_xq(xvB.x, xvB.y, q);
        #pragma unroll
        for (int w = 0; w < 4; ++w) {
            BhP[0].u[w] = 0u; BlP[0].u[w] = xA0;
            BhP[1].u[w] = 0u; BlP[1].u[w] = xB0;
        }
    }

    for (int t2 = 0; t2 < T_STEPS / 2; ++t2) {
        const float4 xnA = xpA[(t2 + 1) & (T_STEPS / 2 - 1)];
        const float4 xnB = xpB[(t2 + 1) & (T_STEPS / 2 - 1)];

        // x parts for steps s0+1 and s0+2 (independent: fill MFMA shadow)
        const unsigned xq1A = make_xq(xvA.z, xvA.w, q);
        const unsigned xq1B = make_xq(xvB.z, xvB.w, q);
        const unsigned xq2A = make_xq(xnA.x, xnA.y, q);
        const unsigned xq2B = make_xq(xnB.x, xnB.y, q);

        lstm_step_dual(BhP, BlP, BhQ, BlQ, cst, A1, A2, biasf, xq1A, xq1B); // s0
        lstm_step_dual(BhQ, BlQ, BhP, BlP, cst, A1, A2, biasf, xq2A, xq2B); // s0+1

        xvA = xnA; xvB = xnB;
    }

    // ---- MLP head per group: z = tanh(W1 h + b1); y = W2 z + b2.
    #pragma unroll
    for (int g = 0; g < 2; ++g) {
        #pragma unroll
        for (int r = 0; r < 4; ++r) {
            const float hval = __uint_as_float(BhP[g].u[r] << 16) +   // hi part
                               __uint_as_float(BlP[g].u[r] << 16);    // lo part (x bits drop)
            hsm[g][wv][e][4 * r + q] = hval;                          // unit 4r+q
        }

        float hv[16];
        #pragma unroll
        for (int j = 0; j < 4; ++j) {
            const float4 t4 = *(const float4*)&hsm[g][wv][e][4 * j];
            hv[4 * j + 0] = t4.x; hv[4 * j + 1] = t4.y;
            hv[4 * j + 2] = t4.z; hv[4 * j + 3] = t4.w;
        }

        float z[4];
        #pragma unroll
        for (int r = 0; r < 4; ++r) {
            const int mm = 4 * q + r;
            float a = b1[mm];
            #pragma unroll
            for (int j = 0; j < 16; ++j) a = fmaf(W1[mm * 16 + j], hv[j], a);
            const float E = fexp2(a * (2.0f * LOG2E));
            z[r] = fmaf(-2.0f, frcp(1.0f + E), 1.0f);   // safe at +-inf
        }
        #pragma unroll
        for (int r = 0; r < 4; ++r) hsm[g][wv][e][4 * q + r] = z[r];

        if (q < 2) {
            float a = b2[q];
            #pragma unroll
            for (int j = 0; j < 16; ++j) a = fmaf(W2[q * 16 + j], hsm[g][wv][e][j], a);
            const int gelem = g ? gelemB : gelemA;
            out[(size_t)gelem * 2 + q] = a;
        }
    }
}

extern "C" void kernel_launch(void* const* d_in, const int* in_sizes, int n_in,
                              void* d_out, int out_size, void* d_ws, size_t ws_size,
                              hipStream_t stream) {
    const float* x    = (const float*)d_in[0];
    const float* W_ih = (const float*)d_in[1];
    const float* W_hh = (const float*)d_in[2];
    const float* b_ih = (const float*)d_in[3];
    const float* b_hh = (const float*)d_in[4];
    const float* W1   = (const float*)d_in[5];
    const float* b1   = (const float*)d_in[6];
    const float* W2   = (const float*)d_in[7];
    const float* b2   = (const float*)d_in[8];
    float* out = (float*)d_out;

    // 32768 elems / 128 per block (4 waves x 2 groups x 16) = 256 blocks
    lstm_mfma_kernel<<<dim3(256), dim3(256), 0, stream>>>(
        x, W_ih, W_hh, b_ih, b_hh, W1, b1, W2, b2, out);
}